// Round 8
// baseline (366.578 us; speedup 1.0000x reference)
//
#include <hip/hip_runtime.h>
#include <hip/hip_fp16.h>
#include <math.h>

#define CDIM 256
#define NE   1024
#define HW   4096            // 64*64
#define NB   16
#define ZQ_SIZE (NB*CDIM*HW) // 16777216

typedef unsigned short ushort_t;
typedef __attribute__((ext_vector_type(8))) _Float16 f16x8;
typedef __attribute__((ext_vector_type(8))) unsigned short u16x8;
typedef __attribute__((ext_vector_type(4))) float f32x4;

#define AS1 __attribute__((address_space(1)))
#define AS3 __attribute__((address_space(3)))

// fp16 1-pass dot error: sigma(d-gap) ~5.2e-6; 6e-5 >= 11 sigma. Safe.
#define MARGIN 6.0e-5f

// ws layout (bytes)
#define WS_EE    0           // 1024 f32
#define WS_ZZ    4096        // 65536 f32
#define WS_CNT   266240      // 1 int (+pad)
#define WS_LIST  266496      // 65536 int
#define WS_ESWZ  528640      // 32 half-slabs x 16384 B fp16 fragment-major
#define WS_NEEDED 1052928

// ---------------- helpers (validated rounds 1-6) ----------------
__device__ __forceinline__ float sq_nofma(float v) {
    float v2 = v * v;
    asm volatile("" : "+v"(v2));
    return v2;
}

template <typename F>
__device__ __forceinline__ float pairwise256_sq(F get) {
    float total = 0.0f;
    #pragma unroll
    for (int h = 0; h < 2; ++h) {
        float r[8];
        #pragma unroll
        for (int j = 0; j < 8; ++j) r[j] = sq_nofma(get(h * 128 + j));
        #pragma unroll
        for (int i = 8; i < 128; i += 8) {
            #pragma unroll
            for (int j = 0; j < 8; ++j) r[j] += sq_nofma(get(h * 128 + i + j));
        }
        float s = ((r[0] + r[1]) + (r[2] + r[3])) + ((r[4] + r[5]) + (r[6] + r[7]));
        total = (h == 0) ? s : (total + s);
    }
    return total;
}

template <typename F>
__device__ __forceinline__ float pairwise128_sq(F get) {
    float r[8];
    #pragma unroll
    for (int j = 0; j < 8; ++j) r[j] = sq_nofma(get(j));
    #pragma unroll
    for (int i = 8; i < 128; i += 8) {
        #pragma unroll
        for (int j = 0; j < 8; ++j) r[j] += sq_nofma(get(i + j));
    }
    return ((r[0] + r[1]) + (r[2] + r[3])) + ((r[4] + r[5]) + (r[6] + r[7]));
}

__device__ __forceinline__ ushort_t f2h(float v) {
    return __half_as_ushort(__float2half(v));   // v_cvt_f16_f32, RNE
}

// ||emb_j||^2 -> ws (standalone; legacy path only)
__global__ __launch_bounds__(256) void ee_kernel(const float* __restrict__ emb,
                                                 float* __restrict__ ee,
                                                 int* __restrict__ cnt) {
    if (blockIdx.x == 0 && threadIdx.x == 0) *cnt = 0;
    int j = blockIdx.x * 256 + threadIdx.x;
    const float* row = emb + (size_t)j * CDIM;
    ee[j] = pairwise256_sq([&](int i) { return row[i]; });
}

// merged: blocks 0..127 = emb fp32->fp16 fragment-major (ks-major halves);
// blocks 128..131 = ee. Half-slab t2 = s*2+ks occupies [t2*16384, +16384):
//   frag (wn,n) at t2*16384 + (wn*2+n)*1024 + (lg*16+lr)*16 + e*2
__global__ __launch_bounds__(256) void ecvt_kernel(const float* __restrict__ emb,
                                                   ushort_t* __restrict__ eswz,
                                                   float* __restrict__ ee,
                                                   int* __restrict__ cnt) {
    if (blockIdx.x >= 128) {
        if (blockIdx.x == 128 && threadIdx.x == 0) *cnt = 0;
        int j = (blockIdx.x - 128) * 256 + threadIdx.x;
        const float* row = emb + (size_t)j * CDIM;
        ee[j] = pairwise256_sq([&](int i) { return row[i]; });
        return;
    }
    int g = blockIdx.x * 256 + threadIdx.x;   // 32768 threads
    int s  = g >> 11;          // slab
    int r  = g & 2047;
    int cw = r >> 3;           // code within chunk 0..255
    int kg = r & 7;            // k-group of 8 within slab
    int chunk = s >> 2, kb = s & 3;
    int wn = cw >> 5, n = (cw >> 4) & 1, lr = cw & 15;
    int ks = kg >> 2, lg = kg & 3;

    const float* src = emb + (size_t)(chunk * 256 + cw) * CDIM + kb * 64 + kg * 8;
    float4 a = *reinterpret_cast<const float4*>(src);
    float4 b = *reinterpret_cast<const float4*>(src + 4);
    u16x8 p = { f2h(a.x), f2h(a.y), f2h(a.z), f2h(a.w),
                f2h(b.x), f2h(b.y), f2h(b.z), f2h(b.w) };
    size_t dst = (size_t)(s * 2 + ks) * 16384 + (wn * 2 + n) * 1024 + (lg * 16 + lr) * 16;
    *reinterpret_cast<u16x8*>((char*)eswz + dst) = p;
}

// ---------------- main MFMA kernel: 512 thr, 8 waves, 64 tokens ----------------
// Half-slab (16 KB) double-buffered E with counted vmcnt(2) + raw barriers
// (T3/T4 minimum recipe). A-frags from LDS. 70.4 KB -> 2 blocks/CU.
__global__ __launch_bounds__(512, 4) void vq_main(const float* __restrict__ z,
                                                  const float* __restrict__ emb,
                                                  const ushort_t* __restrict__ eswz,
                                                  const float* __restrict__ eew,
                                                  float* __restrict__ zzw,
                                                  int* __restrict__ cnt,
                                                  int* __restrict__ list,
                                                  float* __restrict__ out) {
    __shared__ __align__(16) char arena[70400];
    char*  zfB = arena;                     // 32768: z fp16 fragment-major
    char*  esB = arena + 32768;             // 2 x 16384: E half-slab dbuf
    float* eel = (float*)(arena + 65536);   // 1024 f32
    float* zzp = (float*)(arena + 69632);   // 64x2 f32 halves
    int*   rbj = (int*)  (arena + 70144);   // 64
    // post-loop aliases (esB dead after k-loop):
    float* rd1 = (float*)(arena + 32768);   // [8][64]
    int*   rj1 = (int*)  (arena + 34816);
    float* rd2 = (float*)(arena + 36864);

    const int tid  = threadIdx.x;
    const int lane = tid & 63;
    const int wn   = tid >> 6;              // wave 0..7
    const int b    = blockIdx.x >> 6;
    const int hw0  = (blockIdx.x & 63) << 6;
    const float* zb = z + (size_t)b * CDIM * HW + hw0;
    const int lr = lane & 15;
    const int lg = lane >> 4;
    const int laneoff = lane << 4;

    auto issue_half = [&](int t2) {
        const char* gsrc = (const char*)eswz + (size_t)t2 * 16384;
        char* dstb = esB + ((t2 & 1) << 14);
        #pragma unroll
        for (int q = 0; q < 2; ++q)
            __builtin_amdgcn_global_load_lds(
                (const AS1 unsigned*)(gsrc + (q << 13) + (tid << 4)),
                (AS3 unsigned*)(dstb + (q << 13) + (wn << 10)), 16, 0, 0);
    };

    // ---- issue half-slabs 0,1 first (latency hides under z staging) ----
    issue_half(0);
    issue_half(1);

    // ---- prologue: z -> fp16 frag-major, eel, zz halves ----
    {
        const int tok = lane;
        #pragma unroll
        for (int i = 0; i < 4; ++i) {
            int kg = (wn << 2) + i;          // 0..31
            int k0 = kg << 3;
            u16x8 p;
            #pragma unroll
            for (int e = 0; e < 8; ++e)
                p[e] = f2h(zb[(size_t)(k0 + e) * HW + tok]);
            int m = tok >> 4, lrr = tok & 15;
            int kb_ = kg >> 3, ks_ = (kg >> 2) & 1, lg_ = kg & 3;
            int off = (((kb_ * 2 + ks_) * 4 + m) << 10) + ((lg_ * 16 + lrr) << 4);
            *(u16x8*)(zfB + off) = p;
        }
        eel[tid]       = eew[tid];
        eel[tid + 512] = eew[tid + 512];
    }
    if (tid < 128) {   // exact numpy-pairwise halves
        int tok = tid >> 1, h = tid & 1;
        zzp[tok * 2 + h] = pairwise128_sq([&](int i) {
            return zb[(size_t)(h * 128 + i) * HW + tok];
        });
    }
    asm volatile("s_waitcnt lgkmcnt(0)" ::: "memory");
    __builtin_amdgcn_s_barrier();

    f32x4 acc[4][2];
    float sd1[4][4], sd2[4][4];
    int   sj1[4][4];
    #pragma unroll
    for (int m = 0; m < 4; ++m)
        #pragma unroll
        for (int r = 0; r < 4; ++r) { sd1[m][r] = INFINITY; sd2[m][r] = INFINITY; sj1[m][r] = NE; }

    // ---- k-loop: 32 half-slab steps, counted-vmcnt pipeline ----
    #pragma unroll
    for (int t = 0; t < 32; ++t) {
        const int chunk = t >> 3, kb = (t >> 1) & 3, ks = t & 1;
        // slab t landed? (t+1's 2 loads may remain in flight)
        if (t < 31) asm volatile("s_waitcnt vmcnt(2)" ::: "memory");
        else        asm volatile("s_waitcnt vmcnt(0)" ::: "memory");
        __builtin_amdgcn_s_barrier();      // all waves' slab-t loads landed

        if ((t & 7) == 0) {
            #pragma unroll
            for (int m = 0; m < 4; ++m)
                #pragma unroll
                for (int n = 0; n < 2; ++n) acc[m][n] = (f32x4){0.f, 0.f, 0.f, 0.f};
        }
        {
            const char* bufc = esB + ((t & 1) << 14);
            f16x8 ah4[4], bh[2];
            #pragma unroll
            for (int m = 0; m < 4; ++m)
                ah4[m] = *(const f16x8*)(zfB + (((kb * 2 + ks) * 4 + m) << 10) + laneoff);
            #pragma unroll
            for (int n = 0; n < 2; ++n)
                bh[n] = *(const f16x8*)(bufc + ((wn * 2 + n) << 10) + laneoff);
            #pragma unroll
            for (int m = 0; m < 4; ++m)
                #pragma unroll
                for (int n = 0; n < 2; ++n)
                    acc[m][n] = __builtin_amdgcn_mfma_f32_16x16x32_f16(ah4[m], bh[n], acc[m][n], 0, 0, 0);
        }
        if ((t & 7) == 7) {   // chunk epilogue: d = fl(fl(zz+ee) - fl(2*dot)), top-2
            #pragma unroll
            for (int m = 0; m < 4; ++m)
                #pragma unroll
                for (int r = 0; r < 4; ++r) {
                    int tk = m * 16 + lg * 4 + r;
                    float zzv = zzp[2 * tk] + zzp[2 * tk + 1];
                    #pragma unroll
                    for (int n = 0; n < 2; ++n) {
                        int code = (chunk << 8) + (wn << 5) + (n << 4) + lr;
                        float t1 = zzv + eel[code];
                        float d  = t1 - 2.0f * acc[m][n][r];
                        bool lt1 = d < sd1[m][r];
                        bool lt2 = d < sd2[m][r];
                        sd2[m][r] = lt1 ? sd1[m][r] : (lt2 ? d : sd2[m][r]);
                        if (lt1) { sd1[m][r] = d; sj1[m][r] = code; }
                    }
                }
        }
        asm volatile("s_waitcnt lgkmcnt(0)" ::: "memory");
        __builtin_amdgcn_s_barrier();      // all waves done reading buf[t&1]
        if (t < 30) issue_half(t + 2);     // overwrite buf[t&1] for step t+2
    }

    // ---- cross-lane top-2 merge over the 16 code-lanes ----
    #pragma unroll
    for (int off = 1; off <= 8; off <<= 1) {
        #pragma unroll
        for (int m = 0; m < 4; ++m)
            #pragma unroll
            for (int r = 0; r < 4; ++r) {
                float od1 = __shfl_xor(sd1[m][r], off);
                int   oj1 = __shfl_xor(sj1[m][r], off);
                float od2 = __shfl_xor(sd2[m][r], off);
                float nd2 = fminf(fmaxf(sd1[m][r], od1), fminf(sd2[m][r], od2));
                bool tk = (od1 < sd1[m][r]) || (od1 == sd1[m][r] && oj1 < sj1[m][r]);
                if (tk) { sd1[m][r] = od1; sj1[m][r] = oj1; }
                sd2[m][r] = nd2;
            }
    }
    if (lr == 0) {
        #pragma unroll
        for (int m = 0; m < 4; ++m)
            #pragma unroll
            for (int r = 0; r < 4; ++r) {
                int tok = m * 16 + lg * 4 + r;
                rd1[wn * 64 + tok] = sd1[m][r];
                rj1[wn * 64 + tok] = sj1[m][r];
                rd2[wn * 64 + tok] = sd2[m][r];
            }
    }
    __syncthreads();

    // ---- combine 8 waves, decide, emit idx / flag / zz ----
    if (tid < 64) {
        float d1f = rd1[tid]; int j1f = rj1[tid]; float d2f = rd2[tid];
        #pragma unroll
        for (int w = 1; w < 8; ++w) {
            float od1 = rd1[w * 64 + tid];
            int   oj1 = rj1[w * 64 + tid];
            float od2 = rd2[w * 64 + tid];
            float nd2 = fminf(fmaxf(d1f, od1), fminf(d2f, od2));
            bool tk = (od1 < d1f) || (od1 == d1f && oj1 < j1f);
            if (tk) { d1f = od1; j1f = oj1; }
            d2f = nd2;
        }
        rbj[tid] = j1f;
        int gtok = b * HW + hw0 + tid;
        out[(size_t)ZQ_SIZE + gtok] = (float)j1f;
        zzw[gtok] = zzp[2 * tid] + zzp[2 * tid + 1];
        if (!(d2f - d1f > MARGIN)) {
            int slot = atomicAdd(cnt, 1);
            list[slot] = gtok;
        }
    }
    __syncthreads();

    // ---- z_q: gather emb rows -> LDS -> coalesced NCHW ----
    float* zq_st = (float*)arena;   // [64][260] = 66560 B (rbj at 70144 safe)
    {
        int row = tid >> 3, sub = tid & 7;
        int j = rbj[row];
        const float* er = emb + (size_t)j * CDIM;
        #pragma unroll
        for (int i = 0; i < 8; ++i) {
            int c = (sub << 2) + (i << 5);
            float4 v = *reinterpret_cast<const float4*>(er + c);
            *reinterpret_cast<float4*>(&zq_st[row * 260 + c]) = v;
        }
    }
    __syncthreads();
    {
        int tok = tid & 63, cg = tid >> 6;
        float* ob = out + (size_t)b * CDIM * HW + hw0 + tok;
        #pragma unroll 4
        for (int i = 0; i < 32; ++i) {
            int c = (cg << 5) + i;
            ob[(size_t)c * HW] = zq_st[tok * 260 + c];
        }
    }
}

// ---------------- exact fp32 fallback: 8 waves, 8 tokens per staged chunk ----------------
__global__ __launch_bounds__(512) void vq_fallback(const float* __restrict__ z,
                                                   const float* __restrict__ emb,
                                                   const float* __restrict__ eew,
                                                   const float* __restrict__ zzw,
                                                   const int* __restrict__ cnt,
                                                   const int* __restrict__ list,
                                                   float* __restrict__ out) {
    __shared__ __align__(16) float elds[64 * 260];
    __shared__ float zrow[8][256];
    __shared__ int   toks[8];

    const int tid  = threadIdx.x;
    const int lane = tid & 63;
    const int wv   = tid >> 6;           // 8 waves
    const int nt   = *cnt;
    const int groups = (nt + 7) >> 3;

    for (int g = blockIdx.x; g < groups; g += gridDim.x) {
        if (tid < 8) toks[tid] = (g * 8 + tid < nt) ? list[g * 8 + tid] : -1;
        __syncthreads();
        const int gt  = toks[wv];
        const bool act = gt >= 0;
        const int tb  = act ? (gt >> 12) : 0;
        const int thw = act ? (gt & 4095) : 0;
        if (act) {
            #pragma unroll
            for (int i = 0; i < 4; ++i)
                zrow[wv][i * 64 + lane] = z[(size_t)tb * CDIM * HW + (size_t)(i * 64 + lane) * HW + thw];
        }
        const float zz = act ? zzw[gt] : 0.0f;
        float d1 = INFINITY; int j1 = NE;

        for (int c = 0; c < 16; ++c) {
            __syncthreads();
            {   // stage 64 codes x 256 dims with 512 threads
                int row = tid >> 3, sub = tid & 7;
                #pragma unroll
                for (int i = 0; i < 8; ++i) {
                    int col = (sub << 2) + (i << 5);
                    float4 v = *reinterpret_cast<const float4*>(
                        &emb[(size_t)(c * 64 + row) * CDIM + col]);
                    *reinterpret_cast<float4*>(&elds[row * 260 + col]) = v;
                }
            }
            __syncthreads();
            if (act) {
                float acc = 0.0f;
                #pragma unroll 8
                for (int kq = 0; kq < 64; ++kq) {
                    float4 ev = *reinterpret_cast<const float4*>(&elds[lane * 260 + kq * 4]);
                    float4 zv = *reinterpret_cast<const float4*>(&zrow[wv][kq * 4]);
                    acc = fmaf(zv.x, ev.x, acc);
                    acc = fmaf(zv.y, ev.y, acc);
                    acc = fmaf(zv.z, ev.z, acc);
                    acc = fmaf(zv.w, ev.w, acc);
                }
                int j = c * 64 + lane;
                float t1 = zz + eew[j];
                float d  = t1 - 2.0f * acc;
                if (d < d1) { d1 = d; j1 = j; }
            }
        }
        #pragma unroll
        for (int off = 1; off <= 32; off <<= 1) {
            float od = __shfl_xor(d1, off);
            int   oj = __shfl_xor(j1, off);
            if (od < d1 || (od == d1 && oj < j1)) { d1 = od; j1 = oj; }
        }
        if (act) {
            if (lane == 0) out[(size_t)ZQ_SIZE + gt] = (float)j1;
            #pragma unroll
            for (int i = 0; i < 4; ++i) {
                int cc = i * 64 + lane;
                out[(size_t)tb * CDIM * HW + (size_t)cc * HW + thw] = emb[(size_t)j1 * CDIM + cc];
            }
        }
        __syncthreads();
    }
}

// ---------------- legacy round-1 kernel (only if ws too small) ----------------
#define BM 32
#define BN 256
#define BK 16
__global__ __launch_bounds__(256, 3) void vq_legacy(const float* __restrict__ z,
                                                    const float* __restrict__ emb,
                                                    const float* __restrict__ ee,
                                                    float* __restrict__ out) {
    __shared__ float zs[CDIM][BM];
    __shared__ float es[BK][BN];
    __shared__ float ees[BN];
    __shared__ float zzs[BM];
    __shared__ float red_d[4][BM];
    __shared__ int   red_j[4][BM];
    __shared__ int   bestj_s[BM];

    const int tid = threadIdx.x;
    const int b   = blockIdx.x >> 7;
    const int hw0 = (blockIdx.x & 127) << 5;
    const int ti  = tid & 7;
    const int tj  = tid >> 3;
    const int tm0 = ti << 2;
    const int jc0 = tj << 3;
    {
        const float* zb = z + (size_t)b * CDIM * HW + hw0;
        #pragma unroll
        for (int r = 0; r < 8; ++r) {
            int f4 = (r << 8) + tid;
            int c  = f4 >> 3;
            int t4 = (f4 & 7) << 2;
            float4 v = *reinterpret_cast<const float4*>(zb + (size_t)c * HW + t4);
            *reinterpret_cast<float4*>(&zs[c][t4]) = v;
        }
    }
    __syncthreads();
    if (tid < BM) zzs[tid] = pairwise256_sq([&](int i) { return zs[i][tid]; });
    __syncthreads();
    float bd[4]; int bj[4];
    #pragma unroll
    for (int i = 0; i < 4; ++i) { bd[i] = INFINITY; bj[i] = NE; }
    for (int jt = 0; jt < NE / BN; ++jt) {
        const int j0 = jt * BN;
        float acc[4][8];
        #pragma unroll
        for (int i = 0; i < 4; ++i)
            #pragma unroll
            for (int jj = 0; jj < 8; ++jj) acc[i][jj] = 0.0f;
        for (int kt = 0; kt < CDIM / BK; ++kt) {
            __syncthreads();
            #pragma unroll
            for (int r = 0; r < 4; ++r) {
                int f4 = (r << 8) + tid;
                int jj = f4 >> 2;
                int c4 = (f4 & 3) << 2;
                float4 v = *reinterpret_cast<const float4*>(
                    emb + (size_t)(j0 + jj) * CDIM + kt * BK + c4);
                es[c4 + 0][jj] = v.x; es[c4 + 1][jj] = v.y;
                es[c4 + 2][jj] = v.z; es[c4 + 3][jj] = v.w;
            }
            if (kt == 0 && tid < BN) ees[tid] = ee[j0 + tid];
            __syncthreads();
            #pragma unroll
            for (int k = 0; k < BK; ++k) {
                float4 av  = *reinterpret_cast<const float4*>(&zs[kt * BK + k][tm0]);
                float4 bv0 = *reinterpret_cast<const float4*>(&es[k][jc0]);
                float4 bv1 = *reinterpret_cast<const float4*>(&es[k][jc0 + 4]);
                float bb[8] = {bv0.x, bv0.y, bv0.z, bv0.w, bv1.x, bv1.y, bv1.z, bv1.w};
                #pragma unroll
                for (int jj = 0; jj < 8; ++jj) {
                    acc[0][jj] = fmaf(av.x, bb[jj], acc[0][jj]);
                    acc[1][jj] = fmaf(av.y, bb[jj], acc[1][jj]);
                    acc[2][jj] = fmaf(av.z, bb[jj], acc[2][jj]);
                    acc[3][jj] = fmaf(av.w, bb[jj], acc[3][jj]);
                }
            }
        }
        #pragma unroll
        for (int i = 0; i < 4; ++i) {
            float zzv = zzs[tm0 + i];
            #pragma unroll
            for (int jj = 0; jj < 8; ++jj) {
                float t1 = zzv + ees[jc0 + jj];
                float d  = t1 - 2.0f * acc[i][jj];
                if (d < bd[i]) { bd[i] = d; bj[i] = j0 + jc0 + jj; }
            }
        }
    }
    #pragma unroll
    for (int off = 8; off <= 32; off <<= 1) {
        #pragma unroll
        for (int i = 0; i < 4; ++i) {
            float od = __shfl_xor(bd[i], off);
            int   oj = __shfl_xor(bj[i], off);
            if (od < bd[i] || (od == bd[i] && oj < bj[i])) { bd[i] = od; bj[i] = oj; }
        }
    }
    {
        const int lane = tid & 63;
        const int w    = tid >> 6;
        if (lane < 8) {
            #pragma unroll
            for (int i = 0; i < 4; ++i) {
                red_d[w][lane * 4 + i] = bd[i];
                red_j[w][lane * 4 + i] = bj[i];
            }
        }
    }
    __syncthreads();
    if (tid < BM) {
        float d = red_d[0][tid]; int j = red_j[0][tid];
        #pragma unroll
        for (int w2 = 1; w2 < 4; ++w2) {
            float od = red_d[w2][tid]; int oj = red_j[w2][tid];
            if (od < d || (od == d && oj < j)) { d = od; j = oj; }
        }
        bestj_s[tid] = j;
        out[(size_t)ZQ_SIZE + (size_t)b * HW + hw0 + tid] = (float)j;
    }
    __syncthreads();
    {
        const int t  = tid & 31;
        const int c0 = tid >> 5;
        const int jb = bestj_s[t];
        const float* er = emb + (size_t)jb * CDIM;
        float* ob = out + (size_t)b * CDIM * HW + hw0 + t;
        #pragma unroll
        for (int c = c0; c < CDIM; c += 8) ob[(size_t)c * HW] = er[c];
    }
}

extern "C" void kernel_launch(void* const* d_in, const int* in_sizes, int n_in,
                              void* d_out, int out_size, void* d_ws, size_t ws_size,
                              hipStream_t stream) {
    const float* z   = (const float*)d_in[0];
    const float* emb = (const float*)d_in[1];
    float* out = (float*)d_out;
    char*  ws  = (char*)d_ws;

    float*    ee   = (float*)(ws + WS_EE);
    float*    zzw  = (float*)(ws + WS_ZZ);
    int*      cnt  = (int*)  (ws + WS_CNT);
    int*      list = (int*)  (ws + WS_LIST);
    ushort_t* eswz = (ushort_t*)(ws + WS_ESWZ);

    if (ws_size >= (size_t)WS_NEEDED) {
        ecvt_kernel<<<dim3(132), dim3(256), 0, stream>>>(emb, eswz, ee, cnt);
        vq_main<<<dim3((NB * HW) / 64), dim3(512), 0, stream>>>(z, emb, eswz, ee, zzw,
                                                                cnt, list, out);
        vq_fallback<<<dim3(128), dim3(512), 0, stream>>>(z, emb, ee, zzw, cnt, list, out);
    } else {
        ee_kernel<<<dim3(NE / 256), dim3(256), 0, stream>>>(emb, ee, cnt);
        vq_legacy<<<dim3((NB * HW) / BM), dim3(256), 0, stream>>>(z, emb, ee, out);
    }
}

// Round 9
// 256.025 us; speedup vs baseline: 1.4318x; 1.4318x over previous
//
#include <hip/hip_runtime.h>
#include <hip/hip_fp16.h>
#include <math.h>

#define CDIM 256
#define NE   1024
#define HW   4096            // 64*64
#define NB   16
#define ZQ_SIZE (NB*CDIM*HW) // 16777216

typedef unsigned short ushort_t;
typedef __attribute__((ext_vector_type(8))) _Float16 f16x8;
typedef __attribute__((ext_vector_type(8))) unsigned short u16x8;
typedef __attribute__((ext_vector_type(4))) float f32x4;

#define AS1 __attribute__((address_space(1)))
#define AS3 __attribute__((address_space(3)))

// fp16 1-pass dot error: sigma(d-gap) ~5.2e-6; 6e-5 >= 11 sigma. Safe.
// (Empirically absmax 0 in rounds 6-8.)
#define MARGIN 6.0e-5f

// ws layout (bytes)
#define WS_EE    0           // 1024 f32
#define WS_ZZ    4096        // 65536 f32
#define WS_CNT   266240      // 1 int (+pad)
#define WS_LIST  266496      // 65536 int
#define WS_ESWZ  528640      // 32 half-slabs x 16384 B fp16 fragment-major
#define WS_NEEDED 1052928

// ---------------- helpers (validated rounds 1-8) ----------------
__device__ __forceinline__ float sq_nofma(float v) {
    float v2 = v * v;
    asm volatile("" : "+v"(v2));
    return v2;
}

template <typename F>
__device__ __forceinline__ float pairwise256_sq(F get) {
    float total = 0.0f;
    #pragma unroll
    for (int h = 0; h < 2; ++h) {
        float r[8];
        #pragma unroll
        for (int j = 0; j < 8; ++j) r[j] = sq_nofma(get(h * 128 + j));
        #pragma unroll
        for (int i = 8; i < 128; i += 8) {
            #pragma unroll
            for (int j = 0; j < 8; ++j) r[j] += sq_nofma(get(h * 128 + i + j));
        }
        float s = ((r[0] + r[1]) + (r[2] + r[3])) + ((r[4] + r[5]) + (r[6] + r[7]));
        total = (h == 0) ? s : (total + s);
    }
    return total;
}

template <typename F>
__device__ __forceinline__ float pairwise128_sq(F get) {
    float r[8];
    #pragma unroll
    for (int j = 0; j < 8; ++j) r[j] = sq_nofma(get(j));
    #pragma unroll
    for (int i = 8; i < 128; i += 8) {
        #pragma unroll
        for (int j = 0; j < 8; ++j) r[j] += sq_nofma(get(i + j));
    }
    return ((r[0] + r[1]) + (r[2] + r[3])) + ((r[4] + r[5]) + (r[6] + r[7]));
}

__device__ __forceinline__ ushort_t f2h(float v) {
    return __half_as_ushort(__float2half(v));   // v_cvt_f16_f32, RNE
}

// ||emb_j||^2 -> ws (standalone; legacy path only)
__global__ __launch_bounds__(256) void ee_kernel(const float* __restrict__ emb,
                                                 float* __restrict__ ee,
                                                 int* __restrict__ cnt) {
    if (blockIdx.x == 0 && threadIdx.x == 0) *cnt = 0;
    int j = blockIdx.x * 256 + threadIdx.x;
    const float* row = emb + (size_t)j * CDIM;
    ee[j] = pairwise256_sq([&](int i) { return row[i]; });
}

// merged: blocks 0..127 = emb fp32->fp16 fragment-major (ks-major halves);
// blocks 128..131 = ee. Half-slab t2 = s*2+ks occupies [t2*16384, +16384):
//   frag (wn,n) at t2*16384 + (wn*2+n)*1024 + (lg*16+lr)*16 + e*2
__global__ __launch_bounds__(256) void ecvt_kernel(const float* __restrict__ emb,
                                                   ushort_t* __restrict__ eswz,
                                                   float* __restrict__ ee,
                                                   int* __restrict__ cnt) {
    if (blockIdx.x >= 128) {
        if (blockIdx.x == 128 && threadIdx.x == 0) *cnt = 0;
        int j = (blockIdx.x - 128) * 256 + threadIdx.x;
        const float* row = emb + (size_t)j * CDIM;
        ee[j] = pairwise256_sq([&](int i) { return row[i]; });
        return;
    }
    int g = blockIdx.x * 256 + threadIdx.x;   // 32768 threads
    int s  = g >> 11;          // slab
    int r  = g & 2047;
    int cw = r >> 3;           // code within chunk 0..255
    int kg = r & 7;            // k-group of 8 within slab
    int chunk = s >> 2, kb = s & 3;
    int wn = cw >> 5, n = (cw >> 4) & 1, lr = cw & 15;
    int ks = kg >> 2, lg = kg & 3;

    const float* src = emb + (size_t)(chunk * 256 + cw) * CDIM + kb * 64 + kg * 8;
    float4 a = *reinterpret_cast<const float4*>(src);
    float4 b = *reinterpret_cast<const float4*>(src + 4);
    u16x8 p = { f2h(a.x), f2h(a.y), f2h(a.z), f2h(a.w),
                f2h(b.x), f2h(b.y), f2h(b.z), f2h(b.w) };
    size_t dst = (size_t)(s * 2 + ks) * 16384 + (wn * 2 + n) * 1024 + (lg * 16 + lr) * 16;
    *reinterpret_cast<u16x8*>((char*)eswz + dst) = p;
}

// ---------------- main MFMA kernel: 512 thr, 8 waves, 64 tokens ----------------
// Half-slab (16 KB) double-buffered E with counted vmcnt(2) + raw barriers.
// Runtime slab loop (one code copy) + peeled final slab -> no spill.
__global__ __launch_bounds__(512, 4) void vq_main(const float* __restrict__ z,
                                                  const float* __restrict__ emb,
                                                  const ushort_t* __restrict__ eswz,
                                                  const float* __restrict__ eew,
                                                  float* __restrict__ zzw,
                                                  int* __restrict__ cnt,
                                                  int* __restrict__ list,
                                                  float* __restrict__ out) {
    __shared__ __align__(16) char arena[70400];
    char*  zfB = arena;                     // 32768: z fp16 fragment-major
    char*  esB = arena + 32768;             // 2 x 16384: E half-slab dbuf
    float* eel = (float*)(arena + 65536);   // 1024 f32
    float* zzp = (float*)(arena + 69632);   // 64x2 f32 halves
    int*   rbj = (int*)  (arena + 70144);   // 64
    // post-loop aliases (esB dead after k-loop):
    float* rd1 = (float*)(arena + 32768);   // [8][64]
    int*   rj1 = (int*)  (arena + 34816);
    float* rd2 = (float*)(arena + 36864);

    const int tid  = threadIdx.x;
    const int lane = tid & 63;
    const int wn   = tid >> 6;              // wave 0..7
    const int b    = blockIdx.x >> 6;
    const int hw0  = (blockIdx.x & 63) << 6;
    const float* zb = z + (size_t)b * CDIM * HW + hw0;
    const int lr = lane & 15;
    const int lg = lane >> 4;
    const int laneoff = lane << 4;

    auto issue_half = [&](int t2) {
        const char* gsrc = (const char*)eswz + (size_t)t2 * 16384;
        char* dstb = esB + ((t2 & 1) << 14);
        #pragma unroll
        for (int q = 0; q < 2; ++q)
            __builtin_amdgcn_global_load_lds(
                (const AS1 unsigned*)(gsrc + (q << 13) + (tid << 4)),
                (AS3 unsigned*)(dstb + (q << 13) + (wn << 10)), 16, 0, 0);
    };

    // ---- issue half-slabs 0,1 first (latency hides under z staging) ----
    issue_half(0);
    issue_half(1);

    // ---- prologue: z -> fp16 frag-major, eel, zz halves ----
    {
        const int tok = lane;
        #pragma unroll
        for (int i = 0; i < 4; ++i) {
            int kg = (wn << 2) + i;          // 0..31
            int k0 = kg << 3;
            u16x8 p;
            #pragma unroll
            for (int e = 0; e < 8; ++e)
                p[e] = f2h(zb[(size_t)(k0 + e) * HW + tok]);
            int m = tok >> 4, lrr = tok & 15;
            int kb_ = kg >> 3, ks_ = (kg >> 2) & 1, lg_ = kg & 3;
            int off = (((kb_ * 2 + ks_) * 4 + m) << 10) + ((lg_ * 16 + lrr) << 4);
            *(u16x8*)(zfB + off) = p;
        }
        eel[tid]       = eew[tid];
        eel[tid + 512] = eew[tid + 512];
    }
    if (tid < 128) {   // exact numpy-pairwise halves
        int tok = tid >> 1, h = tid & 1;
        zzp[tok * 2 + h] = pairwise128_sq([&](int i) {
            return zb[(size_t)(h * 128 + i) * HW + tok];
        });
    }
    asm volatile("s_waitcnt lgkmcnt(0)" ::: "memory");
    __builtin_amdgcn_s_barrier();

    // per-lane token squared norms (16 tokens/lane), read once
    float zz4[4][4];
    #pragma unroll
    for (int m = 0; m < 4; ++m)
        #pragma unroll
        for (int r = 0; r < 4; ++r) {
            int t = m * 16 + lg * 4 + r;
            zz4[m][r] = zzp[2 * t] + zzp[2 * t + 1];
        }

    f32x4 acc[4][2];
    float sd1[4][4], sd2[4][4];
    int   sj1[4][4];
    #pragma unroll
    for (int m = 0; m < 4; ++m)
        #pragma unroll
        for (int r = 0; r < 4; ++r) { sd1[m][r] = INFINITY; sd2[m][r] = INFINITY; sj1[m][r] = NE; }

    // one half-step: wait -> barrier -> 8 MFMA -> lgkm -> barrier
    auto half_step = [&](int kb, int ks) {
        const char* bufc = esB + (ks << 14);
        f16x8 ah4[4], bh[2];
        #pragma unroll
        for (int m = 0; m < 4; ++m)
            ah4[m] = *(const f16x8*)(zfB + (((kb * 2 + ks) * 4 + m) << 10) + laneoff);
        #pragma unroll
        for (int n = 0; n < 2; ++n)
            bh[n] = *(const f16x8*)(bufc + ((wn * 2 + n) << 10) + laneoff);
        #pragma unroll
        for (int m = 0; m < 4; ++m)
            #pragma unroll
            for (int n = 0; n < 2; ++n)
                acc[m][n] = __builtin_amdgcn_mfma_f32_16x16x32_f16(ah4[m], bh[n], acc[m][n], 0, 0, 0);
    };

    auto epilogue = [&](int chunk) {   // d = fl(fl(zz+ee) - fl(2*dot)), top-2
        #pragma unroll
        for (int m = 0; m < 4; ++m)
            #pragma unroll
            for (int r = 0; r < 4; ++r) {
                float zzv = zz4[m][r];
                #pragma unroll
                for (int n = 0; n < 2; ++n) {
                    int code = (chunk << 8) + (wn << 5) + (n << 4) + lr;
                    float t1 = zzv + eel[code];
                    float d  = t1 - 2.0f * acc[m][n][r];
                    bool lt1 = d < sd1[m][r];
                    bool lt2 = d < sd2[m][r];
                    sd2[m][r] = lt1 ? sd1[m][r] : (lt2 ? d : sd2[m][r]);
                    if (lt1) { sd1[m][r] = d; sj1[m][r] = code; }
                }
            }
    };

    // ---- k-loop: slabs 0..14 runtime (single code copy), slab 15 peeled ----
    for (int s = 0; s < 15; ++s) {
        const int kb = s & 3;
        if (kb == 0) {
            #pragma unroll
            for (int m = 0; m < 4; ++m)
                #pragma unroll
                for (int n = 0; n < 2; ++n) acc[m][n] = (f32x4){0.f, 0.f, 0.f, 0.f};
        }
        #pragma unroll
        for (int ks = 0; ks < 2; ++ks) {
            asm volatile("s_waitcnt vmcnt(2)" ::: "memory");
            __builtin_amdgcn_s_barrier();      // half-slab 2s+ks landed for all
            half_step(kb, ks);
            asm volatile("s_waitcnt lgkmcnt(0)" ::: "memory");
            __builtin_amdgcn_s_barrier();      // all waves done reading buf[ks]
            issue_half(2 * s + ks + 2);        // refill buf[ks]
        }
        if (kb == 3) epilogue(s >> 2);
    }
    // ---- peeled slab 15 (chunk 3, kb 3) ----
    {
        asm volatile("s_waitcnt vmcnt(2)" ::: "memory");   // half 30 landed
        __builtin_amdgcn_s_barrier();
        half_step(3, 0);
        asm volatile("s_waitcnt lgkmcnt(0)" ::: "memory");
        __builtin_amdgcn_s_barrier();
        asm volatile("s_waitcnt vmcnt(0)" ::: "memory");   // half 31 landed
        __builtin_amdgcn_s_barrier();
        half_step(3, 1);
        epilogue(3);
        asm volatile("s_waitcnt lgkmcnt(0)" ::: "memory");
        __builtin_amdgcn_s_barrier();                      // esB free for aliases
    }

    // ---- cross-lane top-2 merge over the 16 code-lanes ----
    #pragma unroll
    for (int off = 1; off <= 8; off <<= 1) {
        #pragma unroll
        for (int m = 0; m < 4; ++m)
            #pragma unroll
            for (int r = 0; r < 4; ++r) {
                float od1 = __shfl_xor(sd1[m][r], off);
                int   oj1 = __shfl_xor(sj1[m][r], off);
                float od2 = __shfl_xor(sd2[m][r], off);
                float nd2 = fminf(fmaxf(sd1[m][r], od1), fminf(sd2[m][r], od2));
                bool tk = (od1 < sd1[m][r]) || (od1 == sd1[m][r] && oj1 < sj1[m][r]);
                if (tk) { sd1[m][r] = od1; sj1[m][r] = oj1; }
                sd2[m][r] = nd2;
            }
    }
    if (lr == 0) {
        #pragma unroll
        for (int m = 0; m < 4; ++m)
            #pragma unroll
            for (int r = 0; r < 4; ++r) {
                int tok = m * 16 + lg * 4 + r;
                rd1[wn * 64 + tok] = sd1[m][r];
                rj1[wn * 64 + tok] = sj1[m][r];
                rd2[wn * 64 + tok] = sd2[m][r];
            }
    }
    __syncthreads();

    // ---- combine 8 waves, decide, emit idx / flag / zz ----
    if (tid < 64) {
        float d1f = rd1[tid]; int j1f = rj1[tid]; float d2f = rd2[tid];
        #pragma unroll
        for (int w = 1; w < 8; ++w) {
            float od1 = rd1[w * 64 + tid];
            int   oj1 = rj1[w * 64 + tid];
            float od2 = rd2[w * 64 + tid];
            float nd2 = fminf(fmaxf(d1f, od1), fminf(d2f, od2));
            bool tk = (od1 < d1f) || (od1 == d1f && oj1 < j1f);
            if (tk) { d1f = od1; j1f = oj1; }
            d2f = nd2;
        }
        rbj[tid] = j1f;
        int gtok = b * HW + hw0 + tid;
        out[(size_t)ZQ_SIZE + gtok] = (float)j1f;
        zzw[gtok] = zzp[2 * tid] + zzp[2 * tid + 1];
        if (!(d2f - d1f > MARGIN)) {
            int slot = atomicAdd(cnt, 1);
            list[slot] = gtok;
        }
    }
    __syncthreads();

    // ---- z_q: gather emb rows -> LDS -> coalesced NCHW ----
    float* zq_st = (float*)arena;   // [64][260] = 66560 B (rbj at 70144 safe)
    {
        int row = tid >> 3, sub = tid & 7;
        int j = rbj[row];
        const float* er = emb + (size_t)j * CDIM;
        #pragma unroll
        for (int i = 0; i < 8; ++i) {
            int c = (sub << 2) + (i << 5);
            float4 v = *reinterpret_cast<const float4*>(er + c);
            *reinterpret_cast<float4*>(&zq_st[row * 260 + c]) = v;
        }
    }
    __syncthreads();
    {
        int tok = tid & 63, cg = tid >> 6;
        float* ob = out + (size_t)b * CDIM * HW + hw0 + tok;
        #pragma unroll 4
        for (int i = 0; i < 32; ++i) {
            int c = (cg << 5) + i;
            ob[(size_t)c * HW] = zq_st[tok * 260 + c];
        }
    }
}

// ---------------- exact fp32 fallback: 8 waves, 8 tokens per staged chunk ----------------
__global__ __launch_bounds__(512) void vq_fallback(const float* __restrict__ z,
                                                   const float* __restrict__ emb,
                                                   const float* __restrict__ eew,
                                                   const float* __restrict__ zzw,
                                                   const int* __restrict__ cnt,
                                                   const int* __restrict__ list,
                                                   float* __restrict__ out) {
    __shared__ __align__(16) float elds[64 * 260];
    __shared__ float zrow[8][256];
    __shared__ int   toks[8];

    const int tid  = threadIdx.x;
    const int lane = tid & 63;
    const int wv   = tid >> 6;           // 8 waves
    const int nt   = *cnt;
    const int groups = (nt + 7) >> 3;

    for (int g = blockIdx.x; g < groups; g += gridDim.x) {
        if (tid < 8) toks[tid] = (g * 8 + tid < nt) ? list[g * 8 + tid] : -1;
        __syncthreads();
        const int gt  = toks[wv];
        const bool act = gt >= 0;
        const int tb  = act ? (gt >> 12) : 0;
        const int thw = act ? (gt & 4095) : 0;
        if (act) {
            #pragma unroll
            for (int i = 0; i < 4; ++i)
                zrow[wv][i * 64 + lane] = z[(size_t)tb * CDIM * HW + (size_t)(i * 64 + lane) * HW + thw];
        }
        const float zz = act ? zzw[gt] : 0.0f;
        float d1 = INFINITY; int j1 = NE;

        for (int c = 0; c < 16; ++c) {
            __syncthreads();
            {   // stage 64 codes x 256 dims with 512 threads
                int row = tid >> 3, sub = tid & 7;
                #pragma unroll
                for (int i = 0; i < 8; ++i) {
                    int col = (sub << 2) + (i << 5);
                    float4 v = *reinterpret_cast<const float4*>(
                        &emb[(size_t)(c * 64 + row) * CDIM + col]);
                    *reinterpret_cast<float4*>(&elds[row * 260 + col]) = v;
                }
            }
            __syncthreads();
            if (act) {
                float acc = 0.0f;
                #pragma unroll 8
                for (int kq = 0; kq < 64; ++kq) {
                    float4 ev = *reinterpret_cast<const float4*>(&elds[lane * 260 + kq * 4]);
                    float4 zv = *reinterpret_cast<const float4*>(&zrow[wv][kq * 4]);
                    acc = fmaf(zv.x, ev.x, acc);
                    acc = fmaf(zv.y, ev.y, acc);
                    acc = fmaf(zv.z, ev.z, acc);
                    acc = fmaf(zv.w, ev.w, acc);
                }
                int j = c * 64 + lane;
                float t1 = zz + eew[j];
                float d  = t1 - 2.0f * acc;
                if (d < d1) { d1 = d; j1 = j; }
            }
        }
        #pragma unroll
        for (int off = 1; off <= 32; off <<= 1) {
            float od = __shfl_xor(d1, off);
            int   oj = __shfl_xor(j1, off);
            if (od < d1 || (od == d1 && oj < j1)) { d1 = od; j1 = oj; }
        }
        if (act) {
            if (lane == 0) out[(size_t)ZQ_SIZE + gt] = (float)j1;
            #pragma unroll
            for (int i = 0; i < 4; ++i) {
                int cc = i * 64 + lane;
                out[(size_t)tb * CDIM * HW + (size_t)cc * HW + thw] = emb[(size_t)j1 * CDIM + cc];
            }
        }
        __syncthreads();
    }
}

// ---------------- legacy round-1 kernel (only if ws too small) ----------------
#define BM 32
#define BN 256
#define BK 16
__global__ __launch_bounds__(256, 3) void vq_legacy(const float* __restrict__ z,
                                                    const float* __restrict__ emb,
                                                    const float* __restrict__ ee,
                                                    float* __restrict__ out) {
    __shared__ float zs[CDIM][BM];
    __shared__ float es[BK][BN];
    __shared__ float ees[BN];
    __shared__ float zzs[BM];
    __shared__ float red_d[4][BM];
    __shared__ int   red_j[4][BM];
    __shared__ int   bestj_s[BM];

    const int tid = threadIdx.x;
    const int b   = blockIdx.x >> 7;
    const int hw0 = (blockIdx.x & 127) << 5;
    const int ti  = tid & 7;
    const int tj  = tid >> 3;
    const int tm0 = ti << 2;
    const int jc0 = tj << 3;
    {
        const float* zb = z + (size_t)b * CDIM * HW + hw0;
        #pragma unroll
        for (int r = 0; r < 8; ++r) {
            int f4 = (r << 8) + tid;
            int c  = f4 >> 3;
            int t4 = (f4 & 7) << 2;
            float4 v = *reinterpret_cast<const float4*>(zb + (size_t)c * HW + t4);
            *reinterpret_cast<float4*>(&zs[c][t4]) = v;
        }
    }
    __syncthreads();
    if (tid < BM) zzs[tid] = pairwise256_sq([&](int i) { return zs[i][tid]; });
    __syncthreads();
    float bd[4]; int bj[4];
    #pragma unroll
    for (int i = 0; i < 4; ++i) { bd[i] = INFINITY; bj[i] = NE; }
    for (int jt = 0; jt < NE / BN; ++jt) {
        const int j0 = jt * BN;
        float acc[4][8];
        #pragma unroll
        for (int i = 0; i < 4; ++i)
            #pragma unroll
            for (int jj = 0; jj < 8; ++jj) acc[i][jj] = 0.0f;
        for (int kt = 0; kt < CDIM / BK; ++kt) {
            __syncthreads();
            #pragma unroll
            for (int r = 0; r < 4; ++r) {
                int f4 = (r << 8) + tid;
                int jj = f4 >> 2;
                int c4 = (f4 & 3) << 2;
                float4 v = *reinterpret_cast<const float4*>(
                    emb + (size_t)(j0 + jj) * CDIM + kt * BK + c4);
                es[c4 + 0][jj] = v.x; es[c4 + 1][jj] = v.y;
                es[c4 + 2][jj] = v.z; es[c4 + 3][jj] = v.w;
            }
            if (kt == 0 && tid < BN) ees[tid] = ee[j0 + tid];
            __syncthreads();
            #pragma unroll
            for (int k = 0; k < BK; ++k) {
                float4 av  = *reinterpret_cast<const float4*>(&zs[kt * BK + k][tm0]);
                float4 bv0 = *reinterpret_cast<const float4*>(&es[k][jc0]);
                float4 bv1 = *reinterpret_cast<const float4*>(&es[k][jc0 + 4]);
                float bb[8] = {bv0.x, bv0.y, bv0.z, bv0.w, bv1.x, bv1.y, bv1.z, bv1.w};
                #pragma unroll
                for (int jj = 0; jj < 8; ++jj) {
                    acc[0][jj] = fmaf(av.x, bb[jj], acc[0][jj]);
                    acc[1][jj] = fmaf(av.y, bb[jj], acc[1][jj]);
                    acc[2][jj] = fmaf(av.z, bb[jj], acc[2][jj]);
                    acc[3][jj] = fmaf(av.w, bb[jj], acc[3][jj]);
                }
            }
        }
        #pragma unroll
        for (int i = 0; i < 4; ++i) {
            float zzv = zzs[tm0 + i];
            #pragma unroll
            for (int jj = 0; jj < 8; ++jj) {
                float t1 = zzv + ees[jc0 + jj];
                float d  = t1 - 2.0f * acc[i][jj];
                if (d < bd[i]) { bd[i] = d; bj[i] = j0 + jc0 + jj; }
            }
        }
    }
    #pragma unroll
    for (int off = 8; off <= 32; off <<= 1) {
        #pragma unroll
        for (int i = 0; i < 4; ++i) {
            float od = __shfl_xor(bd[i], off);
            int   oj = __shfl_xor(bj[i], off);
            if (od < bd[i] || (od == bd[i] && oj < bj[i])) { bd[i] = od; bj[i] = oj; }
        }
    }
    {
        const int lane = tid & 63;
        const int w    = tid >> 6;
        if (lane < 8) {
            #pragma unroll
            for (int i = 0; i < 4; ++i) {
                red_d[w][lane * 4 + i] = bd[i];
                red_j[w][lane * 4 + i] = bj[i];
            }
        }
    }
    __syncthreads();
    if (tid < BM) {
        float d = red_d[0][tid]; int j = red_j[0][tid];
        #pragma unroll
        for (int w2 = 1; w2 < 4; ++w2) {
            float od = red_d[w2][tid]; int oj = red_j[w2][tid];
            if (od < d || (od == d && oj < j)) { d = od; j = oj; }
        }
        bestj_s[tid] = j;
        out[(size_t)ZQ_SIZE + (size_t)b * HW + hw0 + tid] = (float)j;
    }
    __syncthreads();
    {
        const int t  = tid & 31;
        const int c0 = tid >> 5;
        const int jb = bestj_s[t];
        const float* er = emb + (size_t)jb * CDIM;
        float* ob = out + (size_t)b * CDIM * HW + hw0 + t;
        #pragma unroll
        for (int c = c0; c < CDIM; c += 8) ob[(size_t)c * HW] = er[c];
    }
}

extern "C" void kernel_launch(void* const* d_in, const int* in_sizes, int n_in,
                              void* d_out, int out_size, void* d_ws, size_t ws_size,
                              hipStream_t stream) {
    const float* z   = (const float*)d_in[0];
    const float* emb = (const float*)d_in[1];
    float* out = (float*)d_out;
    char*  ws  = (char*)d_ws;

    float*    ee   = (float*)(ws + WS_EE);
    float*    zzw  = (float*)(ws + WS_ZZ);
    int*      cnt  = (int*)  (ws + WS_CNT);
    int*      list = (int*)  (ws + WS_LIST);
    ushort_t* eswz = (ushort_t*)(ws + WS_ESWZ);

    if (ws_size >= (size_t)WS_NEEDED) {
        ecvt_kernel<<<dim3(132), dim3(256), 0, stream>>>(emb, eswz, ee, cnt);
        vq_main<<<dim3((NB * HW) / 64), dim3(512), 0, stream>>>(z, emb, eswz, ee, zzw,
                                                                cnt, list, out);
        vq_fallback<<<dim3(128), dim3(512), 0, stream>>>(z, emb, ee, zzw, cnt, list, out);
    } else {
        ee_kernel<<<dim3(NE / 256), dim3(256), 0, stream>>>(emb, ee, cnt);
        vq_legacy<<<dim3((NB * HW) / BM), dim3(256), 0, stream>>>(z, emb, ee, out);
    }
}

// Round 10
// 250.113 us; speedup vs baseline: 1.4657x; 1.0236x over previous
//
#include <hip/hip_runtime.h>
#include <hip/hip_fp16.h>
#include <math.h>

#define CDIM 256
#define NE   1024
#define HW   4096            // 64*64
#define NB   16
#define ZQ_SIZE (NB*CDIM*HW) // 16777216

typedef unsigned short ushort_t;
typedef __attribute__((ext_vector_type(8))) _Float16 f16x8;
typedef __attribute__((ext_vector_type(8))) unsigned short u16x8;
typedef __attribute__((ext_vector_type(4))) float f32x4;

#define AS1 __attribute__((address_space(1)))
#define AS3 __attribute__((address_space(3)))

// s-space margin: |d_ref-gap - s-gap| <= fl(zz+ee) rounding (3.05e-5)
// + final-sub rounding (3.05e-5) + 2*fp16-dot worst (~2.1e-5) ~= 8.2e-5.
// 1.5e-4 covers it; reference ties (true gap <= 6e-5) are always flagged.
#define MARGIN 1.5e-4f

// ws layout (bytes)
#define WS_EE    0           // 1024 f32
#define WS_ZZ    4096        // 65536 f32
#define WS_CNT   266240      // 1 int (+pad)
#define WS_LIST  266496      // 65536 int
#define WS_ESWZ  528640      // 32 half-slabs x 16384 B fp16 fragment-major
#define WS_NEEDED 1052928

// ---------------- helpers (validated rounds 1-9) ----------------
__device__ __forceinline__ float sq_nofma(float v) {
    float v2 = v * v;
    asm volatile("" : "+v"(v2));
    return v2;
}

template <typename F>
__device__ __forceinline__ float pairwise256_sq(F get) {
    float total = 0.0f;
    #pragma unroll
    for (int h = 0; h < 2; ++h) {
        float r[8];
        #pragma unroll
        for (int j = 0; j < 8; ++j) r[j] = sq_nofma(get(h * 128 + j));
        #pragma unroll
        for (int i = 8; i < 128; i += 8) {
            #pragma unroll
            for (int j = 0; j < 8; ++j) r[j] += sq_nofma(get(h * 128 + i + j));
        }
        float s = ((r[0] + r[1]) + (r[2] + r[3])) + ((r[4] + r[5]) + (r[6] + r[7]));
        total = (h == 0) ? s : (total + s);
    }
    return total;
}

template <typename F>
__device__ __forceinline__ float pairwise128_sq(F get) {
    float r[8];
    #pragma unroll
    for (int j = 0; j < 8; ++j) r[j] = sq_nofma(get(j));
    #pragma unroll
    for (int i = 8; i < 128; i += 8) {
        #pragma unroll
        for (int j = 0; j < 8; ++j) r[j] += sq_nofma(get(i + j));
    }
    return ((r[0] + r[1]) + (r[2] + r[3])) + ((r[4] + r[5]) + (r[6] + r[7]));
}

__device__ __forceinline__ ushort_t f2h(float v) {
    return __half_as_ushort(__float2half(v));   // v_cvt_f16_f32, RNE
}

// ||emb_j||^2 -> ws (standalone; legacy path only)
__global__ __launch_bounds__(256) void ee_kernel(const float* __restrict__ emb,
                                                 float* __restrict__ ee,
                                                 int* __restrict__ cnt) {
    if (blockIdx.x == 0 && threadIdx.x == 0) *cnt = 0;
    int j = blockIdx.x * 256 + threadIdx.x;
    const float* row = emb + (size_t)j * CDIM;
    ee[j] = pairwise256_sq([&](int i) { return row[i]; });
}

// merged: blocks 0..127 = emb fp32->fp16 fragment-major (ks-major halves);
// blocks 128..131 = ee. Half-slab t2 = s*2+ks occupies [t2*16384, +16384):
//   frag f = (code within chunk)>>4, at t2*16384 + f*1024 + (lg*16+lr)*16 + e*2
__global__ __launch_bounds__(256) void ecvt_kernel(const float* __restrict__ emb,
                                                   ushort_t* __restrict__ eswz,
                                                   float* __restrict__ ee,
                                                   int* __restrict__ cnt) {
    if (blockIdx.x >= 128) {
        if (blockIdx.x == 128 && threadIdx.x == 0) *cnt = 0;
        int j = (blockIdx.x - 128) * 256 + threadIdx.x;
        const float* row = emb + (size_t)j * CDIM;
        ee[j] = pairwise256_sq([&](int i) { return row[i]; });
        return;
    }
    int g = blockIdx.x * 256 + threadIdx.x;   // 32768 threads
    int s  = g >> 11;          // slab
    int r  = g & 2047;
    int cw = r >> 3;           // code within chunk 0..255
    int kg = r & 7;            // k-group of 8 within slab
    int chunk = s >> 2, kb = s & 3;
    int f  = cw >> 4, lr = cw & 15;
    int ks = kg >> 2, lg = kg & 3;

    const float* src = emb + (size_t)(chunk * 256 + cw) * CDIM + kb * 64 + kg * 8;
    float4 a = *reinterpret_cast<const float4*>(src);
    float4 b = *reinterpret_cast<const float4*>(src + 4);
    u16x8 p = { f2h(a.x), f2h(a.y), f2h(a.z), f2h(a.w),
                f2h(b.x), f2h(b.y), f2h(b.z), f2h(b.w) };
    size_t dst = (size_t)(s * 2 + ks) * 16384 + f * 1024 + (lg * 16 + lr) * 16;
    *reinterpret_cast<u16x8*>((char*)eswz + dst) = p;
}

// ---------------- main MFMA kernel: 512 thr, 8 waves, 64 tokens ----------------
// Wave (h,g): token-half h (32 tokens), code-group g (64 codes). Per lane:
// 8 tokens of top-2 state (24 regs), acc 2x4 (32 AGPR) -> no spill at 64 VGPR.
// Half-slab (16 KB) dbuf E, counted vmcnt(2) + raw barriers (round-9 schedule).
__global__ __launch_bounds__(512, 4) void vq_main(const float* __restrict__ z,
                                                  const float* __restrict__ emb,
                                                  const ushort_t* __restrict__ eswz,
                                                  const float* __restrict__ eew,
                                                  float* __restrict__ zzw,
                                                  int* __restrict__ cnt,
                                                  int* __restrict__ list,
                                                  float* __restrict__ out) {
    __shared__ __align__(16) char arena[70400];
    char*  zfB = arena;                     // 32768: z fp16 fragment-major
    char*  esB = arena + 32768;             // 2 x 16384: E half-slab dbuf
    float* eel = (float*)(arena + 65536);   // 1024 f32
    float* zzp = (float*)(arena + 69632);   // 64x2 f32 halves
    int*   rbj = (int*)  (arena + 70144);   // 64
    // post-loop aliases (esB dead after k-loop): [4][64] each
    float* rd1 = (float*)(arena + 32768);
    int*   rj1 = (int*)  (arena + 33792);
    float* rd2 = (float*)(arena + 34816);

    const int tid  = threadIdx.x;
    const int lane = tid & 63;
    const int wn   = tid >> 6;              // wave 0..7
    const int hh   = wn & 1;                // token half
    const int gg   = wn >> 1;               // code group 0..3
    const int b    = blockIdx.x >> 6;
    const int hw0  = (blockIdx.x & 63) << 6;
    const float* zb = z + (size_t)b * CDIM * HW + hw0;
    const int lr = lane & 15;
    const int lg = lane >> 4;
    const int laneoff = lane << 4;

    auto issue_half = [&](int t2) {
        const char* gsrc = (const char*)eswz + (size_t)t2 * 16384;
        char* dstb = esB + ((t2 & 1) << 14);
        #pragma unroll
        for (int q = 0; q < 2; ++q)
            __builtin_amdgcn_global_load_lds(
                (const AS1 unsigned*)(gsrc + (q << 13) + (tid << 4)),
                (AS3 unsigned*)(dstb + (q << 13) + (wn << 10)), 16, 0, 0);
    };

    // ---- issue half-slabs 0,1 first (latency hides under z staging) ----
    issue_half(0);
    issue_half(1);

    // ---- prologue: z -> fp16 frag-major, eel, zz halves ----
    {
        const int tok = lane;
        #pragma unroll
        for (int i = 0; i < 4; ++i) {
            int kg = (wn << 2) + i;          // 0..31
            int k0 = kg << 3;
            u16x8 p;
            #pragma unroll
            for (int e = 0; e < 8; ++e)
                p[e] = f2h(zb[(size_t)(k0 + e) * HW + tok]);
            int m = tok >> 4, lrr = tok & 15;
            int kb_ = kg >> 3, ks_ = (kg >> 2) & 1, lg_ = kg & 3;
            int off = (((kb_ * 2 + ks_) * 4 + m) << 10) + ((lg_ * 16 + lrr) << 4);
            *(u16x8*)(zfB + off) = p;
        }
        eel[tid]       = eew[tid];
        eel[tid + 512] = eew[tid + 512];
    }
    if (tid < 128) {   // exact numpy-pairwise halves
        int tok = tid >> 1, h = tid & 1;
        zzp[tok * 2 + h] = pairwise128_sq([&](int i) {
            return zb[(size_t)(h * 128 + i) * HW + tok];
        });
    }
    asm volatile("s_waitcnt lgkmcnt(0)" ::: "memory");
    __builtin_amdgcn_s_barrier();

    f32x4 acc[2][4];
    float sd1[2][4], sd2[2][4];
    int   sj1[2][4];
    #pragma unroll
    for (int m = 0; m < 2; ++m)
        #pragma unroll
        for (int r = 0; r < 4; ++r) { sd1[m][r] = INFINITY; sd2[m][r] = INFINITY; sj1[m][r] = NE; }

    // one half-step: 2 A-frags (this wave's token half) x 4 B-frags (code group)
    auto half_step = [&](int kb, int ks) {
        const char* bufc = esB + (ks << 14);
        f16x8 ah2[2], bh[4];
        #pragma unroll
        for (int m = 0; m < 2; ++m)
            ah2[m] = *(const f16x8*)(zfB + (((kb * 2 + ks) * 4 + hh * 2 + m) << 10) + laneoff);
        #pragma unroll
        for (int n = 0; n < 4; ++n)
            bh[n] = *(const f16x8*)(bufc + (((gg << 2) + n) << 10) + laneoff);
        #pragma unroll
        for (int m = 0; m < 2; ++m)
            #pragma unroll
            for (int n = 0; n < 4; ++n)
                acc[m][n] = __builtin_amdgcn_mfma_f32_16x16x32_f16(ah2[m], bh[n], acc[m][n], 0, 0, 0);
    };

    // chunk epilogue: s = ee - 2*dot (zz dropped: token-constant), top-2
    auto epilogue = [&](int chunk) {
        #pragma unroll
        for (int n = 0; n < 4; ++n) {
            int code = (chunk << 8) + (gg << 6) + (n << 4) + lr;
            float eev = eel[code];
            #pragma unroll
            for (int m = 0; m < 2; ++m)
                #pragma unroll
                for (int r = 0; r < 4; ++r) {
                    float d = eev - 2.0f * acc[m][n][r];
                    bool lt1 = d < sd1[m][r];
                    bool lt2 = d < sd2[m][r];
                    sd2[m][r] = lt1 ? sd1[m][r] : (lt2 ? d : sd2[m][r]);
                    if (lt1) { sd1[m][r] = d; sj1[m][r] = code; }
                }
        }
    };

    // ---- k-loop: slabs 0..14 runtime (single code copy), slab 15 peeled ----
    for (int s = 0; s < 15; ++s) {
        const int kb = s & 3;
        if (kb == 0) {
            #pragma unroll
            for (int m = 0; m < 2; ++m)
                #pragma unroll
                for (int n = 0; n < 4; ++n) acc[m][n] = (f32x4){0.f, 0.f, 0.f, 0.f};
        }
        #pragma unroll
        for (int ks = 0; ks < 2; ++ks) {
            asm volatile("s_waitcnt vmcnt(2)" ::: "memory");
            __builtin_amdgcn_s_barrier();      // half-slab 2s+ks landed for all
            half_step(kb, ks);
            asm volatile("s_waitcnt lgkmcnt(0)" ::: "memory");
            __builtin_amdgcn_s_barrier();      // all waves done reading buf[ks]
            issue_half(2 * s + ks + 2);        // refill buf[ks]
        }
        if (kb == 3) epilogue(s >> 2);
    }
    // ---- peeled slab 15 (chunk 3, kb 3) ----
    {
        asm volatile("s_waitcnt vmcnt(2)" ::: "memory");   // half 30 landed
        __builtin_amdgcn_s_barrier();
        half_step(3, 0);
        asm volatile("s_waitcnt lgkmcnt(0)" ::: "memory");
        __builtin_amdgcn_s_barrier();
        asm volatile("s_waitcnt vmcnt(0)" ::: "memory");   // half 31 landed
        __builtin_amdgcn_s_barrier();
        half_step(3, 1);
        epilogue(3);
        asm volatile("s_waitcnt lgkmcnt(0)" ::: "memory");
        __builtin_amdgcn_s_barrier();                      // esB free for aliases
    }

    // ---- cross-lane top-2 merge over the 16 code-lanes ----
    #pragma unroll
    for (int off = 1; off <= 8; off <<= 1) {
        #pragma unroll
        for (int m = 0; m < 2; ++m)
            #pragma unroll
            for (int r = 0; r < 4; ++r) {
                float od1 = __shfl_xor(sd1[m][r], off);
                int   oj1 = __shfl_xor(sj1[m][r], off);
                float od2 = __shfl_xor(sd2[m][r], off);
                float nd2 = fminf(fmaxf(sd1[m][r], od1), fminf(sd2[m][r], od2));
                bool tk = (od1 < sd1[m][r]) || (od1 == sd1[m][r] && oj1 < sj1[m][r]);
                if (tk) { sd1[m][r] = od1; sj1[m][r] = oj1; }
                sd2[m][r] = nd2;
            }
    }
    if (lr == 0) {
        #pragma unroll
        for (int m = 0; m < 2; ++m)
            #pragma unroll
            for (int r = 0; r < 4; ++r) {
                int tok = hh * 32 + m * 16 + lg * 4 + r;
                rd1[gg * 64 + tok] = sd1[m][r];
                rj1[gg * 64 + tok] = sj1[m][r];
                rd2[gg * 64 + tok] = sd2[m][r];
            }
    }
    __syncthreads();

    // ---- combine 4 code-groups, decide, emit idx / flag / zz ----
    if (tid < 64) {
        float d1f = rd1[tid]; int j1f = rj1[tid]; float d2f = rd2[tid];
        #pragma unroll
        for (int w = 1; w < 4; ++w) {
            float od1 = rd1[w * 64 + tid];
            int   oj1 = rj1[w * 64 + tid];
            float od2 = rd2[w * 64 + tid];
            float nd2 = fminf(fmaxf(d1f, od1), fminf(d2f, od2));
            bool tk = (od1 < d1f) || (od1 == d1f && oj1 < j1f);
            if (tk) { d1f = od1; j1f = oj1; }
            d2f = nd2;
        }
        rbj[tid] = j1f;
        int gtok = b * HW + hw0 + tid;
        out[(size_t)ZQ_SIZE + gtok] = (float)j1f;
        zzw[gtok] = zzp[2 * tid] + zzp[2 * tid + 1];
        if (!(d2f - d1f > MARGIN)) {
            int slot = atomicAdd(cnt, 1);
            list[slot] = gtok;
        }
    }
    __syncthreads();

    // ---- z_q: gather emb rows -> LDS -> coalesced NCHW ----
    float* zq_st = (float*)arena;   // [64][260] = 66560 B (rbj at 70144 safe)
    {
        int row = tid >> 3, sub = tid & 7;
        int j = rbj[row];
        const float* er = emb + (size_t)j * CDIM;
        #pragma unroll
        for (int i = 0; i < 8; ++i) {
            int c = (sub << 2) + (i << 5);
            float4 v = *reinterpret_cast<const float4*>(er + c);
            *reinterpret_cast<float4*>(&zq_st[row * 260 + c]) = v;
        }
    }
    __syncthreads();
    {
        int tok = tid & 63, cg = tid >> 6;
        float* ob = out + (size_t)b * CDIM * HW + hw0 + tok;
        #pragma unroll 4
        for (int i = 0; i < 32; ++i) {
            int c = (cg << 5) + i;
            ob[(size_t)c * HW] = zq_st[tok * 260 + c];
        }
    }
}

// ---------------- exact fp32 fallback: 8 waves, 8 tokens per staged chunk ----------------
__global__ __launch_bounds__(512) void vq_fallback(const float* __restrict__ z,
                                                   const float* __restrict__ emb,
                                                   const float* __restrict__ eew,
                                                   const float* __restrict__ zzw,
                                                   const int* __restrict__ cnt,
                                                   const int* __restrict__ list,
                                                   float* __restrict__ out) {
    __shared__ __align__(16) float elds[64 * 260];
    __shared__ float zrow[8][256];
    __shared__ int   toks[8];

    const int tid  = threadIdx.x;
    const int lane = tid & 63;
    const int wv   = tid >> 6;           // 8 waves
    const int nt   = *cnt;
    const int groups = (nt + 7) >> 3;

    for (int g = blockIdx.x; g < groups; g += gridDim.x) {
        if (tid < 8) toks[tid] = (g * 8 + tid < nt) ? list[g * 8 + tid] : -1;
        __syncthreads();
        const int gt  = toks[wv];
        const bool act = gt >= 0;
        const int tb  = act ? (gt >> 12) : 0;
        const int thw = act ? (gt & 4095) : 0;
        if (act) {
            #pragma unroll
            for (int i = 0; i < 4; ++i)
                zrow[wv][i * 64 + lane] = z[(size_t)tb * CDIM * HW + (size_t)(i * 64 + lane) * HW + thw];
        }
        const float zz = act ? zzw[gt] : 0.0f;
        float d1 = INFINITY; int j1 = NE;

        for (int c = 0; c < 16; ++c) {
            __syncthreads();
            {   // stage 64 codes x 256 dims with 512 threads
                int row = tid >> 3, sub = tid & 7;
                #pragma unroll
                for (int i = 0; i < 8; ++i) {
                    int col = (sub << 2) + (i << 5);
                    float4 v = *reinterpret_cast<const float4*>(
                        &emb[(size_t)(c * 64 + row) * CDIM + col]);
                    *reinterpret_cast<float4*>(&elds[row * 260 + col]) = v;
                }
            }
            __syncthreads();
            if (act) {
                float acc = 0.0f;
                #pragma unroll 8
                for (int kq = 0; kq < 64; ++kq) {
                    float4 ev = *reinterpret_cast<const float4*>(&elds[lane * 260 + kq * 4]);
                    float4 zv = *reinterpret_cast<const float4*>(&zrow[wv][kq * 4]);
                    acc = fmaf(zv.x, ev.x, acc);
                    acc = fmaf(zv.y, ev.y, acc);
                    acc = fmaf(zv.z, ev.z, acc);
                    acc = fmaf(zv.w, ev.w, acc);
                }
                int j = c * 64 + lane;
                float t1 = zz + eew[j];
                float d  = t1 - 2.0f * acc;
                if (d < d1) { d1 = d; j1 = j; }
            }
        }
        #pragma unroll
        for (int off = 1; off <= 32; off <<= 1) {
            float od = __shfl_xor(d1, off);
            int   oj = __shfl_xor(j1, off);
            if (od < d1 || (od == d1 && oj < j1)) { d1 = od; j1 = oj; }
        }
        if (act) {
            if (lane == 0) out[(size_t)ZQ_SIZE + gt] = (float)j1;
            #pragma unroll
            for (int i = 0; i < 4; ++i) {
                int cc = i * 64 + lane;
                out[(size_t)tb * CDIM * HW + (size_t)cc * HW + thw] = emb[(size_t)j1 * CDIM + cc];
            }
        }
        __syncthreads();
    }
}

// ---------------- legacy round-1 kernel (only if ws too small) ----------------
#define BM 32
#define BN 256
#define BK 16
__global__ __launch_bounds__(256, 3) void vq_legacy(const float* __restrict__ z,
                                                    const float* __restrict__ emb,
                                                    const float* __restrict__ ee,
                                                    float* __restrict__ out) {
    __shared__ float zs[CDIM][BM];
    __shared__ float es[BK][BN];
    __shared__ float ees[BN];
    __shared__ float zzs[BM];
    __shared__ float red_d[4][BM];
    __shared__ int   red_j[4][BM];
    __shared__ int   bestj_s[BM];

    const int tid = threadIdx.x;
    const int b   = blockIdx.x >> 7;
    const int hw0 = (blockIdx.x & 127) << 5;
    const int ti  = tid & 7;
    const int tj  = tid >> 3;
    const int tm0 = ti << 2;
    const int jc0 = tj << 3;
    {
        const float* zb = z + (size_t)b * CDIM * HW + hw0;
        #pragma unroll
        for (int r = 0; r < 8; ++r) {
            int f4 = (r << 8) + tid;
            int c  = f4 >> 3;
            int t4 = (f4 & 7) << 2;
            float4 v = *reinterpret_cast<const float4*>(zb + (size_t)c * HW + t4);
            *reinterpret_cast<float4*>(&zs[c][t4]) = v;
        }
    }
    __syncthreads();
    if (tid < BM) zzs[tid] = pairwise256_sq([&](int i) { return zs[i][tid]; });
    __syncthreads();
    float bd[4]; int bj[4];
    #pragma unroll
    for (int i = 0; i < 4; ++i) { bd[i] = INFINITY; bj[i] = NE; }
    for (int jt = 0; jt < NE / BN; ++jt) {
        const int j0 = jt * BN;
        float acc[4][8];
        #pragma unroll
        for (int i = 0; i < 4; ++i)
            #pragma unroll
            for (int jj = 0; jj < 8; ++jj) acc[i][jj] = 0.0f;
        for (int kt = 0; kt < CDIM / BK; ++kt) {
            __syncthreads();
            #pragma unroll
            for (int r = 0; r < 4; ++r) {
                int f4 = (r << 8) + tid;
                int jj = f4 >> 2;
                int c4 = (f4 & 3) << 2;
                float4 v = *reinterpret_cast<const float4*>(
                    emb + (size_t)(j0 + jj) * CDIM + kt * BK + c4);
                es[c4 + 0][jj] = v.x; es[c4 + 1][jj] = v.y;
                es[c4 + 2][jj] = v.z; es[c4 + 3][jj] = v.w;
            }
            if (kt == 0 && tid < BN) ees[tid] = ee[j0 + tid];
            __syncthreads();
            #pragma unroll
            for (int k = 0; k < BK; ++k) {
                float4 av  = *reinterpret_cast<const float4*>(&zs[kt * BK + k][tm0]);
                float4 bv0 = *reinterpret_cast<const float4*>(&es[k][jc0]);
                float4 bv1 = *reinterpret_cast<const float4*>(&es[k][jc0 + 4]);
                float bb[8] = {bv0.x, bv0.y, bv0.z, bv0.w, bv1.x, bv1.y, bv1.z, bv1.w};
                #pragma unroll
                for (int jj = 0; jj < 8; ++jj) {
                    acc[0][jj] = fmaf(av.x, bb[jj], acc[0][jj]);
                    acc[1][jj] = fmaf(av.y, bb[jj], acc[1][jj]);
                    acc[2][jj] = fmaf(av.z, bb[jj], acc[2][jj]);
                    acc[3][jj] = fmaf(av.w, bb[jj], acc[3][jj]);
                }
            }
        }
        #pragma unroll
        for (int i = 0; i < 4; ++i) {
            float zzv = zzs[tm0 + i];
            #pragma unroll
            for (int jj = 0; jj < 8; ++jj) {
                float t1 = zzv + ees[jc0 + jj];
                float d  = t1 - 2.0f * acc[i][jj];
                if (d < bd[i]) { bd[i] = d; bj[i] = j0 + jc0 + jj; }
            }
        }
    }
    #pragma unroll
    for (int off = 8; off <= 32; off <<= 1) {
        #pragma unroll
        for (int i = 0; i < 4; ++i) {
            float od = __shfl_xor(bd[i], off);
            int   oj = __shfl_xor(bj[i], off);
            if (od < bd[i] || (od == bd[i] && oj < bj[i])) { bd[i] = od; bj[i] = oj; }
        }
    }
    {
        const int lane = tid & 63;
        const int w    = tid >> 6;
        if (lane < 8) {
            #pragma unroll
            for (int i = 0; i < 4; ++i) {
                red_d[w][lane * 4 + i] = bd[i];
                red_j[w][lane * 4 + i] = bj[i];
            }
        }
    }
    __syncthreads();
    if (tid < BM) {
        float d = red_d[0][tid]; int j = red_j[0][tid];
        #pragma unroll
        for (int w2 = 1; w2 < 4; ++w2) {
            float od = red_d[w2][tid]; int oj = red_j[w2][tid];
            if (od < d || (od == d && oj < j)) { d = od; j = oj; }
        }
        bestj_s[tid] = j;
        out[(size_t)ZQ_SIZE + (size_t)b * HW + hw0 + tid] = (float)j;
    }
    __syncthreads();
    {
        const int t  = tid & 31;
        const int c0 = tid >> 5;
        const int jb = bestj_s[t];
        const float* er = emb + (size_t)jb * CDIM;
        float* ob = out + (size_t)b * CDIM * HW + hw0 + t;
        #pragma unroll
        for (int c = c0; c < CDIM; c += 8) ob[(size_t)c * HW] = er[c];
    }
}

extern "C" void kernel_launch(void* const* d_in, const int* in_sizes, int n_in,
                              void* d_out, int out_size, void* d_ws, size_t ws_size,
                              hipStream_t stream) {
    const float* z   = (const float*)d_in[0];
    const float* emb = (const float*)d_in[1];
    float* out = (float*)d_out;
    char*  ws  = (char*)d_ws;

    float*    ee   = (float*)(ws + WS_EE);
    float*    zzw  = (float*)(ws + WS_ZZ);
    int*      cnt  = (int*)  (ws + WS_CNT);
    int*      list = (int*)  (ws + WS_LIST);
    ushort_t* eswz = (ushort_t*)(ws + WS_ESWZ);

    if (ws_size >= (size_t)WS_NEEDED) {
        ecvt_kernel<<<dim3(132), dim3(256), 0, stream>>>(emb, eswz, ee, cnt);
        vq_main<<<dim3((NB * HW) / 64), dim3(512), 0, stream>>>(z, emb, eswz, ee, zzw,
                                                                cnt, list, out);
        vq_fallback<<<dim3(128), dim3(512), 0, stream>>>(z, emb, ee, zzw, cnt, list, out);
    } else {
        ee_kernel<<<dim3(NE / 256), dim3(256), 0, stream>>>(emb, ee, cnt);
        vq_legacy<<<dim3((NB * HW) / BM), dim3(256), 0, stream>>>(z, emb, ee, out);
    }
}